// Round 1
// baseline (936.255 us; speedup 1.0000x reference)
//
#include <hip/hip_runtime.h>
#include <math.h>

#define HH 64

// ---------------- degree / normalization ----------------

__global__ void k_init_deg(float* __restrict__ deg, int n) {
    int i = blockIdx.x * blockDim.x + threadIdx.x;
    if (i < n) deg[i] = 1.0f;   // self-loop contributes 1
}

__global__ void k_edge_deg(const int* __restrict__ col, int E, float* __restrict__ deg) {
    int e = blockIdx.x * blockDim.x + threadIdx.x;
    if (e < E) atomicAdd(&deg[col[e]], 1.0f);
}

__global__ void k_dinv(float* __restrict__ deg, int n) {
    int i = blockIdx.x * blockDim.x + threadIdx.x;
    if (i < n) deg[i] = rsqrtf(deg[i]);   // deg >= 1 always (self-loops)
}

// ---------------- dense transform + self-loop init ----------------
// One wave per node, lane = output feature. Writes lin = h@W and
// agg initialized with the self-loop message dinv[n]^2 * lin.
template<int FIN>
__global__ void k_gemm_selfloop(const float* __restrict__ x, const float* __restrict__ W,
                                const float* __restrict__ dinv,
                                float* __restrict__ lin, float* __restrict__ agg, int n) {
    int node = blockIdx.x * (blockDim.x >> 6) + (threadIdx.x >> 6);
    int t = threadIdx.x & 63;
    if (node >= n) return;
    const float* xr = x + (size_t)node * FIN;
    float acc = 0.f;
#pragma unroll 8
    for (int k = 0; k < FIN; ++k) acc = fmaf(xr[k], W[k * HH + t], acc);
    lin[(size_t)node * HH + t] = acc;
    float di = dinv[node];
    agg[(size_t)node * HH + t] = di * di * acc;
}

// ---------------- edge scatter-add ----------------
// One wave per edge, lane = feature. agg[col] += dinv[row]*dinv[col]*lin[row]
__global__ void k_edge_agg(const int* __restrict__ row, const int* __restrict__ col,
                           const float* __restrict__ dinv, const float* __restrict__ lin,
                           float* __restrict__ agg, int E) {
    int e = blockIdx.x * (blockDim.x >> 6) + (threadIdx.x >> 6);
    int lane = threadIdx.x & 63;
    if (e >= E) return;
    int r = row[e], c = col[e];
    float w = dinv[r] * dinv[c];
    atomicAdd(&agg[(size_t)c * HH + lane], w * lin[(size_t)r * HH + lane]);
}

// ---------------- bias + L2 normalize + ReLU ----------------
__global__ void k_epilogue(const float* __restrict__ agg, const float* __restrict__ b,
                           float* __restrict__ hout, int n) {
    int node = blockIdx.x * (blockDim.x >> 6) + (threadIdx.x >> 6);
    int lane = threadIdx.x & 63;
    if (node >= n) return;
    float v = agg[(size_t)node * HH + lane] + b[lane];
    float ss = v * v;
#pragma unroll
    for (int off = 1; off < 64; off <<= 1) ss += __shfl_xor(ss, off, 64);
    float nrm = sqrtf(ss);
    v = v / fmaxf(nrm, 1e-12f);
    hout[(size_t)node * HH + lane] = fmaxf(v, 0.f);
}

// ---------------- pool + classifier + softmax ----------------
// One block (64 threads) per graph. batch[] is sorted -> binary search range.
__global__ void k_final(const float* __restrict__ node_emb, const int* __restrict__ batch,
                        const float* __restrict__ Wm, const float* __restrict__ bm,
                        float* __restrict__ logits, float* __restrict__ probs,
                        float* __restrict__ graph_emb, int n) {
    int g = blockIdx.x;
    int lane = threadIdx.x;
    // start = lower_bound(batch, g), end = lower_bound(batch, g+1)
    int lo = 0, hi = n;
    while (lo < hi) { int mid = (lo + hi) >> 1; if (batch[mid] < g) lo = mid + 1; else hi = mid; }
    int start = lo;
    lo = start; hi = n;
    while (lo < hi) { int mid = (lo + hi) >> 1; if (batch[mid] < g + 1) lo = mid + 1; else hi = mid; }
    int end = lo;

    float s = 0.f;
    for (int node = start; node < end; ++node) s += node_emb[(size_t)node * HH + lane];
    float cnt = (float)(end - start);
    float mean = s / fmaxf(cnt, 1.0f);
    graph_emb[(size_t)g * HH + lane] = mean;

    __shared__ float semb[HH];
    __shared__ float slog[16];
    semb[lane] = mean;
    __syncthreads();
    if (lane < 10) {
        float acc = bm[lane];
        for (int k = 0; k < HH; ++k) acc = fmaf(semb[k], Wm[k * 10 + lane], acc);
        slog[lane] = acc;
    }
    __syncthreads();
    if (lane < 10) {
        float mx = -1e30f;
        for (int j = 0; j < 10; ++j) mx = fmaxf(mx, slog[j]);
        float den = 0.f;
        for (int j = 0; j < 10; ++j) den += __expf(slog[j] - mx);
        float lg = slog[lane];
        logits[g * 10 + lane] = lg;
        probs[g * 10 + lane] = __expf(lg - mx) / den;
    }
}

// ---------------- launch ----------------

extern "C" void kernel_launch(void* const* d_in, const int* in_sizes, int n_in,
                              void* d_out, int out_size, void* d_ws, size_t ws_size,
                              hipStream_t stream) {
    const float* x     = (const float*)d_in[0];
    const int*   ei    = (const int*)  d_in[1];
    const int*   batch = (const int*)  d_in[2];
    const float* W1 = (const float*)d_in[3];  const float* b1 = (const float*)d_in[4];
    const float* W2 = (const float*)d_in[5];  const float* b2 = (const float*)d_in[6];
    const float* W3 = (const float*)d_in[7];  const float* b3 = (const float*)d_in[8];
    const float* Wm = (const float*)d_in[9];  const float* bm = (const float*)d_in[10];

    const int N = in_sizes[2];          // 50000 nodes
    const int E = in_sizes[1] / 2;      // 800000 edges
    const int G = (out_size - N * HH) / (2 * 10 + HH);  // 256 graphs

    const int* row = ei;       // edge_index[0] : source
    const int* col = ei + E;   // edge_index[1] : aggregation target

    float* out       = (float*)d_out;
    float* logits    = out;
    float* probs     = out + (size_t)G * 10;
    float* node_emb  = out + (size_t)2 * G * 10;
    float* graph_emb = node_emb + (size_t)N * HH;

    // workspace layout
    char* w = (char*)d_ws;
    size_t dinv_bytes = (((size_t)N * 4) + 255) & ~(size_t)255;
    float* dinv = (float*)w;
    float* bufA = (float*)(w + dinv_bytes);          // lin
    float* bufB = bufA + (size_t)N * HH;             // agg
    float* bufC = bufB + (size_t)N * HH;             // h (layer output)

    const int B = 256;
    dim3 blk(B);
    int node_blocks = (N + 3) / 4;   // 4 waves/block, 1 node/wave
    int edge_blocks = (E + 3) / 4;

    // normalization
    k_init_deg<<<(N + B - 1) / B, blk, 0, stream>>>(dinv, N);
    k_edge_deg<<<(E + B - 1) / B, blk, 0, stream>>>(col, E, dinv);
    k_dinv<<<(N + B - 1) / B, blk, 0, stream>>>(dinv, N);

    // layer 1 (FIN=128)
    k_gemm_selfloop<128><<<node_blocks, blk, 0, stream>>>(x, W1, dinv, bufA, bufB, N);
    k_edge_agg<<<edge_blocks, blk, 0, stream>>>(row, col, dinv, bufA, bufB, E);
    k_epilogue<<<node_blocks, blk, 0, stream>>>(bufB, b1, bufC, N);

    // layer 2 (FIN=64)
    k_gemm_selfloop<64><<<node_blocks, blk, 0, stream>>>(bufC, W2, dinv, bufA, bufB, N);
    k_edge_agg<<<edge_blocks, blk, 0, stream>>>(row, col, dinv, bufA, bufB, E);
    k_epilogue<<<node_blocks, blk, 0, stream>>>(bufB, b2, bufC, N);

    // layer 3 (FIN=64) -> node_emb in d_out
    k_gemm_selfloop<64><<<node_blocks, blk, 0, stream>>>(bufC, W3, dinv, bufA, bufB, N);
    k_edge_agg<<<edge_blocks, blk, 0, stream>>>(row, col, dinv, bufA, bufB, E);
    k_epilogue<<<node_blocks, blk, 0, stream>>>(bufB, b3, node_emb, N);

    // pool + classifier
    k_final<<<G, dim3(64), 0, stream>>>(node_emb, batch, Wm, bm, logits, probs, graph_emb, N);
}

// Round 2
// 599.508 us; speedup vs baseline: 1.5617x; 1.5617x over previous
//
#include <hip/hip_runtime.h>
#include <math.h>

#define HH 64

// ---------------- CSR build ----------------

__global__ void k_zero_int(int* __restrict__ p, int n) {
    int i = blockIdx.x * blockDim.x + threadIdx.x;
    if (i < n) p[i] = 0;
}

__global__ void k_count(const int* __restrict__ col, int E, int* __restrict__ cnt) {
    int e = blockIdx.x * blockDim.x + threadIdx.x;
    if (e < E) atomicAdd(&cnt[col[e]], 1);
}

// Single-block exclusive scan over cnt -> rowptr, fill; also dinv = rsqrt(cnt+1).
__global__ void k_scan(const int* __restrict__ cnt, int* __restrict__ rowptr,
                       int* __restrict__ fill, float* __restrict__ dinv, int n) {
    __shared__ int buf[1024];
    __shared__ int carry;
    if (threadIdx.x == 0) carry = 0;
    __syncthreads();
    for (int base = 0; base < n; base += 1024) {
        int i = base + threadIdx.x;
        int orig = (i < n) ? cnt[i] : 0;
        buf[threadIdx.x] = orig;
        __syncthreads();
#pragma unroll
        for (int off = 1; off < 1024; off <<= 1) {
            int t = (threadIdx.x >= off) ? buf[threadIdx.x - off] : 0;
            __syncthreads();
            buf[threadIdx.x] += t;
            __syncthreads();
        }
        int excl = buf[threadIdx.x] - orig + carry;
        if (i < n) {
            rowptr[i] = excl;
            fill[i]   = excl;
            dinv[i]   = rsqrtf((float)(orig + 1));   // +1 self-loop
        }
        __syncthreads();
        if (threadIdx.x == 1023) carry += buf[1023];
        __syncthreads();
    }
    if (threadIdx.x == 0) rowptr[n] = carry;
}

__global__ void k_fill(const int* __restrict__ row, const int* __restrict__ col,
                       const float* __restrict__ dinv, int E,
                       int* __restrict__ fill, int* __restrict__ csr_src,
                       float* __restrict__ csr_w) {
    int e = blockIdx.x * blockDim.x + threadIdx.x;
    if (e >= E) return;
    int r = row[e], c = col[e];
    int dst = atomicAdd(&fill[c], 1);
    csr_src[dst] = r;
    csr_w[dst]   = dinv[r] * dinv[c];
}

// ---------------- dense transform ----------------
// One wave per node, lane = output feature. x row held in registers,
// broadcast via shfl; W column loads are coalesced and L1-hot.
template<int FIN>
__global__ void k_gemm(const float* __restrict__ x, const float* __restrict__ W,
                       float* __restrict__ lin, int n) {
    int node = blockIdx.x * (blockDim.x >> 6) + (threadIdx.x >> 6);
    int t = threadIdx.x & 63;
    if (node >= n) return;
    const float* xr = x + (size_t)node * FIN;
    float xv[FIN / 64];
#pragma unroll
    for (int u = 0; u < FIN / 64; ++u) xv[u] = xr[u * 64 + t];
    float acc = 0.f;
#pragma unroll
    for (int u = 0; u < FIN / 64; ++u) {
#pragma unroll
        for (int k = 0; k < 64; ++k) {
            acc = fmaf(__shfl(xv[u], k, 64), W[(u * 64 + k) * HH + t], acc);
        }
    }
    lin[(size_t)node * HH + t] = acc;
}

// ---------------- gather aggregation + bias + L2norm + ReLU ----------------
// One wave per node. Edge metadata loaded 64-wide then broadcast via shfl.
__global__ void k_gather(const float* __restrict__ lin, const int* __restrict__ csr_src,
                         const float* __restrict__ csr_w, const int* __restrict__ rowptr,
                         const float* __restrict__ dinv, const float* __restrict__ b,
                         float* __restrict__ hout, int n) {
    int node = blockIdx.x * (blockDim.x >> 6) + (threadIdx.x >> 6);
    int lane = threadIdx.x & 63;
    if (node >= n) return;
    int start = rowptr[node], end = rowptr[node + 1];
    float di = dinv[node];
    float acc0 = di * di * lin[(size_t)node * HH + lane];   // self-loop
    float acc1 = 0.f;
    for (int base = start; base < end; base += 64) {
        int m = end - base; if (m > 64) m = 64;
        int   sv = (base + lane < end) ? csr_src[base + lane] : 0;
        float wv = (base + lane < end) ? csr_w[base + lane]   : 0.f;
        int j = 0;
        for (; j + 1 < m; j += 2) {
            int   s0 = __shfl(sv, j, 64);     float w0 = __shfl(wv, j, 64);
            int   s1 = __shfl(sv, j + 1, 64); float w1 = __shfl(wv, j + 1, 64);
            acc0 = fmaf(w0, lin[(size_t)s0 * HH + lane], acc0);
            acc1 = fmaf(w1, lin[(size_t)s1 * HH + lane], acc1);
        }
        if (j < m) {
            int s0 = __shfl(sv, j, 64); float w0 = __shfl(wv, j, 64);
            acc0 = fmaf(w0, lin[(size_t)s0 * HH + lane], acc0);
        }
    }
    float v = acc0 + acc1 + b[lane];
    float ss = v * v;
#pragma unroll
    for (int off = 1; off < 64; off <<= 1) ss += __shfl_xor(ss, off, 64);
    v = v / fmaxf(sqrtf(ss), 1e-12f);
    hout[(size_t)node * HH + lane] = fmaxf(v, 0.f);
}

// ---------------- pool + classifier + softmax ----------------
__global__ void k_final(const float* __restrict__ node_emb, const int* __restrict__ batch,
                        const float* __restrict__ Wm, const float* __restrict__ bm,
                        float* __restrict__ logits, float* __restrict__ probs,
                        float* __restrict__ graph_emb, int n) {
    int g = blockIdx.x;
    int lane = threadIdx.x;
    int lo = 0, hi = n;
    while (lo < hi) { int mid = (lo + hi) >> 1; if (batch[mid] < g) lo = mid + 1; else hi = mid; }
    int start = lo;
    lo = start; hi = n;
    while (lo < hi) { int mid = (lo + hi) >> 1; if (batch[mid] < g + 1) lo = mid + 1; else hi = mid; }
    int end = lo;

    float s = 0.f;
    for (int node = start; node < end; ++node) s += node_emb[(size_t)node * HH + lane];
    float cnt = (float)(end - start);
    float mean = s / fmaxf(cnt, 1.0f);
    graph_emb[(size_t)g * HH + lane] = mean;

    __shared__ float semb[HH];
    __shared__ float slog[16];
    semb[lane] = mean;
    __syncthreads();
    if (lane < 10) {
        float acc = bm[lane];
        for (int k = 0; k < HH; ++k) acc = fmaf(semb[k], Wm[k * 10 + lane], acc);
        slog[lane] = acc;
    }
    __syncthreads();
    if (lane < 10) {
        float mx = -1e30f;
        for (int j = 0; j < 10; ++j) mx = fmaxf(mx, slog[j]);
        float den = 0.f;
        for (int j = 0; j < 10; ++j) den += __expf(slog[j] - mx);
        float lg = slog[lane];
        logits[g * 10 + lane] = lg;
        probs[g * 10 + lane] = __expf(lg - mx) / den;
    }
}

// ---------------- launch ----------------

extern "C" void kernel_launch(void* const* d_in, const int* in_sizes, int n_in,
                              void* d_out, int out_size, void* d_ws, size_t ws_size,
                              hipStream_t stream) {
    const float* x     = (const float*)d_in[0];
    const int*   ei    = (const int*)  d_in[1];
    const int*   batch = (const int*)  d_in[2];
    const float* W1 = (const float*)d_in[3];  const float* b1 = (const float*)d_in[4];
    const float* W2 = (const float*)d_in[5];  const float* b2 = (const float*)d_in[6];
    const float* W3 = (const float*)d_in[7];  const float* b3 = (const float*)d_in[8];
    const float* Wm = (const float*)d_in[9];  const float* bm = (const float*)d_in[10];

    const int N = in_sizes[2];
    const int E = in_sizes[1] / 2;
    const int G = (out_size - N * HH) / (2 * 10 + HH);

    const int* row = ei;
    const int* col = ei + E;

    float* out       = (float*)d_out;
    float* logits    = out;
    float* probs     = out + (size_t)G * 10;
    float* node_emb  = out + (size_t)2 * G * 10;
    float* graph_emb = node_emb + (size_t)N * HH;

    // workspace layout (256B aligned slices)
    char* w = (char*)d_ws;
    auto alloc = [&](size_t bytes) { char* p = w; w += (bytes + 255) & ~(size_t)255; return p; };
    float* dinv    = (float*)alloc((size_t)N * 4);
    int*   cnt     = (int*)  alloc((size_t)N * 4);
    int*   rowptr  = (int*)  alloc(((size_t)N + 1) * 4);
    int*   fill    = (int*)  alloc((size_t)N * 4);
    int*   csr_src = (int*)  alloc((size_t)E * 4);
    float* csr_w   = (float*)alloc((size_t)E * 4);
    float* lin     = (float*)alloc((size_t)N * HH * 4);
    float* hbuf    = (float*)alloc((size_t)N * HH * 4);

    const int B = 256;
    dim3 blk(B);
    int node_blocks = (N + 3) / 4;   // 4 waves/block, 1 node/wave
    int nB = (N + B - 1) / B;
    int eB = (E + B - 1) / B;

    // CSR build + normalization
    k_zero_int<<<nB, blk, 0, stream>>>(cnt, N);
    k_count<<<eB, blk, 0, stream>>>(col, E, cnt);
    k_scan<<<1, dim3(1024), 0, stream>>>(cnt, rowptr, fill, dinv, N);
    k_fill<<<eB, blk, 0, stream>>>(row, col, dinv, E, fill, csr_src, csr_w);

    // layer 1 (FIN=128)
    k_gemm<128><<<node_blocks, blk, 0, stream>>>(x, W1, lin, N);
    k_gather<<<node_blocks, blk, 0, stream>>>(lin, csr_src, csr_w, rowptr, dinv, b1, hbuf, N);
    // layer 2
    k_gemm<64><<<node_blocks, blk, 0, stream>>>(hbuf, W2, lin, N);
    k_gather<<<node_blocks, blk, 0, stream>>>(lin, csr_src, csr_w, rowptr, dinv, b2, hbuf, N);
    // layer 3 -> node_emb
    k_gemm<64><<<node_blocks, blk, 0, stream>>>(hbuf, W3, lin, N);
    k_gather<<<node_blocks, blk, 0, stream>>>(lin, csr_src, csr_w, rowptr, dinv, b3, node_emb, N);

    // pool + classifier
    k_final<<<G, dim3(64), 0, stream>>>(node_emb, batch, Wm, bm, logits, probs, graph_emb, N);
}

// Round 3
// 511.020 us; speedup vs baseline: 1.8321x; 1.1732x over previous
//
#include <hip/hip_runtime.h>
#include <math.h>

#define HH 64
#define SCAN_B 1024

// ---------------- CSR build ----------------

__global__ void k_zero_int(int* __restrict__ p, int n) {
    int i = blockIdx.x * blockDim.x + threadIdx.x;
    if (i < n) p[i] = 0;
}

__global__ void k_count(const int* __restrict__ col, int E, int* __restrict__ cnt) {
    int e = blockIdx.x * blockDim.x + threadIdx.x;
    if (e < E) atomicAdd(&cnt[col[e]], 1);
}

// Phase 1: per-block sum of a 1024-chunk of cnt.
__global__ void k_scan_reduce(const int* __restrict__ cnt, int n, int* __restrict__ partial) {
    int i = blockIdx.x * SCAN_B + threadIdx.x;
    int v = (i < n) ? cnt[i] : 0;
#pragma unroll
    for (int off = 1; off < 64; off <<= 1) v += __shfl_xor(v, off, 64);
    __shared__ int ws[SCAN_B / 64];
    if ((threadIdx.x & 63) == 0) ws[threadIdx.x >> 6] = v;
    __syncthreads();
    if (threadIdx.x == 0) {
        int s = 0;
#pragma unroll
        for (int j = 0; j < SCAN_B / 64; ++j) s += ws[j];
        partial[blockIdx.x] = s;
    }
}

// Phase 2: single small block exclusive-scans partials in place; writes rowptr[n]=total.
__global__ void k_scan_partials(int* __restrict__ partial, int nb, int* __restrict__ rowptr, int n) {
    __shared__ int buf[1024];
    int tid = threadIdx.x;
    int orig = (tid < nb) ? partial[tid] : 0;
    buf[tid] = orig;
    __syncthreads();
#pragma unroll
    for (int off = 1; off < 1024; off <<= 1) {
        int t = (tid >= off) ? buf[tid - off] : 0;
        __syncthreads();
        buf[tid] += t;
        __syncthreads();
    }
    if (tid < nb) partial[tid] = buf[tid] - orig;   // exclusive
    if (tid == nb - 1) rowptr[n] = buf[tid];        // total = E
}

// Phase 3: per-block LDS scan + offset; writes rowptr, fill, dinv.
__global__ void k_scan_apply(const int* __restrict__ cnt, const int* __restrict__ partial,
                             int n, int* __restrict__ rowptr, int* __restrict__ fill,
                             float* __restrict__ dinv) {
    __shared__ int buf[SCAN_B];
    int tid = threadIdx.x;
    int i = blockIdx.x * SCAN_B + tid;
    int orig = (i < n) ? cnt[i] : 0;
    buf[tid] = orig;
    __syncthreads();
#pragma unroll
    for (int off = 1; off < SCAN_B; off <<= 1) {
        int t = (tid >= off) ? buf[tid - off] : 0;
        __syncthreads();
        buf[tid] += t;
        __syncthreads();
    }
    if (i < n) {
        int excl = buf[tid] - orig + partial[blockIdx.x];
        rowptr[i] = excl;
        fill[i]   = excl;
        dinv[i]   = rsqrtf((float)(orig + 1));   // +1 self-loop
    }
}

__global__ void k_fill(const int* __restrict__ row, const int* __restrict__ col,
                       const float* __restrict__ dinv, int E,
                       int* __restrict__ fill, int* __restrict__ csr_src,
                       float* __restrict__ csr_w) {
    int e = blockIdx.x * blockDim.x + threadIdx.x;
    if (e >= E) return;
    int r = row[e], c = col[e];
    int dst = atomicAdd(&fill[c], 1);
    csr_src[dst] = r;
    csr_w[dst]   = dinv[r] * dinv[c];
}

// ---------------- dense transform ----------------
template<int FIN>
__global__ void k_gemm(const float* __restrict__ x, const float* __restrict__ W,
                       float* __restrict__ lin, int n) {
    int node = blockIdx.x * (blockDim.x >> 6) + (threadIdx.x >> 6);
    int t = threadIdx.x & 63;
    if (node >= n) return;
    const float* xr = x + (size_t)node * FIN;
    float xv[FIN / 64];
#pragma unroll
    for (int u = 0; u < FIN / 64; ++u) xv[u] = xr[u * 64 + t];
    float acc = 0.f;
#pragma unroll
    for (int u = 0; u < FIN / 64; ++u) {
#pragma unroll
        for (int k = 0; k < 64; ++k) {
            acc = fmaf(__shfl(xv[u], k, 64), W[(u * 64 + k) * HH + t], acc);
        }
    }
    lin[(size_t)node * HH + t] = acc;
}

// ---------------- gather aggregation + bias + L2norm + ReLU ----------------
__global__ void k_gather(const float* __restrict__ lin, const int* __restrict__ csr_src,
                         const float* __restrict__ csr_w, const int* __restrict__ rowptr,
                         const float* __restrict__ dinv, const float* __restrict__ b,
                         float* __restrict__ hout, int n) {
    int node = blockIdx.x * (blockDim.x >> 6) + (threadIdx.x >> 6);
    int lane = threadIdx.x & 63;
    if (node >= n) return;
    int start = rowptr[node], end = rowptr[node + 1];
    float di = dinv[node];
    float acc0 = di * di * lin[(size_t)node * HH + lane];   // self-loop
    float acc1 = 0.f;
    for (int base = start; base < end; base += 64) {
        int m = end - base; if (m > 64) m = 64;
        int   sv = (base + lane < end) ? csr_src[base + lane] : 0;
        float wv = (base + lane < end) ? csr_w[base + lane]   : 0.f;
        int j = 0;
        for (; j + 1 < m; j += 2) {
            int   s0 = __shfl(sv, j, 64);     float w0 = __shfl(wv, j, 64);
            int   s1 = __shfl(sv, j + 1, 64); float w1 = __shfl(wv, j + 1, 64);
            acc0 = fmaf(w0, lin[(size_t)s0 * HH + lane], acc0);
            acc1 = fmaf(w1, lin[(size_t)s1 * HH + lane], acc1);
        }
        if (j < m) {
            int s0 = __shfl(sv, j, 64); float w0 = __shfl(wv, j, 64);
            acc0 = fmaf(w0, lin[(size_t)s0 * HH + lane], acc0);
        }
    }
    float v = acc0 + acc1 + b[lane];
    float ss = v * v;
#pragma unroll
    for (int off = 1; off < 64; off <<= 1) ss += __shfl_xor(ss, off, 64);
    v = v / fmaxf(sqrtf(ss), 1e-12f);
    hout[(size_t)node * HH + lane] = fmaxf(v, 0.f);
}

// ---------------- pool + classifier + softmax ----------------
__global__ void k_final(const float* __restrict__ node_emb, const int* __restrict__ batch,
                        const float* __restrict__ Wm, const float* __restrict__ bm,
                        float* __restrict__ logits, float* __restrict__ probs,
                        float* __restrict__ graph_emb, int n) {
    int g = blockIdx.x;
    int lane = threadIdx.x;
    int lo = 0, hi = n;
    while (lo < hi) { int mid = (lo + hi) >> 1; if (batch[mid] < g) lo = mid + 1; else hi = mid; }
    int start = lo;
    lo = start; hi = n;
    while (lo < hi) { int mid = (lo + hi) >> 1; if (batch[mid] < g + 1) lo = mid + 1; else hi = mid; }
    int end = lo;

    float s = 0.f;
    for (int node = start; node < end; ++node) s += node_emb[(size_t)node * HH + lane];
    float cnt = (float)(end - start);
    float mean = s / fmaxf(cnt, 1.0f);
    graph_emb[(size_t)g * HH + lane] = mean;

    __shared__ float semb[HH];
    __shared__ float slog[16];
    semb[lane] = mean;
    __syncthreads();
    if (lane < 10) {
        float acc = bm[lane];
        for (int k = 0; k < HH; ++k) acc = fmaf(semb[k], Wm[k * 10 + lane], acc);
        slog[lane] = acc;
    }
    __syncthreads();
    if (lane < 10) {
        float mx = -1e30f;
        for (int j = 0; j < 10; ++j) mx = fmaxf(mx, slog[j]);
        float den = 0.f;
        for (int j = 0; j < 10; ++j) den += __expf(slog[j] - mx);
        float lg = slog[lane];
        logits[g * 10 + lane] = lg;
        probs[g * 10 + lane] = __expf(lg - mx) / den;
    }
}

// ---------------- launch ----------------

extern "C" void kernel_launch(void* const* d_in, const int* in_sizes, int n_in,
                              void* d_out, int out_size, void* d_ws, size_t ws_size,
                              hipStream_t stream) {
    const float* x     = (const float*)d_in[0];
    const int*   ei    = (const int*)  d_in[1];
    const int*   batch = (const int*)  d_in[2];
    const float* W1 = (const float*)d_in[3];  const float* b1 = (const float*)d_in[4];
    const float* W2 = (const float*)d_in[5];  const float* b2 = (const float*)d_in[6];
    const float* W3 = (const float*)d_in[7];  const float* b3 = (const float*)d_in[8];
    const float* Wm = (const float*)d_in[9];  const float* bm = (const float*)d_in[10];

    const int N = in_sizes[2];
    const int E = in_sizes[1] / 2;
    const int G = (out_size - N * HH) / (2 * 10 + HH);

    const int* row = ei;
    const int* col = ei + E;

    float* out       = (float*)d_out;
    float* logits    = out;
    float* probs     = out + (size_t)G * 10;
    float* node_emb  = out + (size_t)2 * G * 10;
    float* graph_emb = node_emb + (size_t)N * HH;

    // workspace layout (256B aligned slices)
    char* w = (char*)d_ws;
    auto alloc = [&](size_t bytes) { char* p = w; w += (bytes + 255) & ~(size_t)255; return p; };
    float* dinv    = (float*)alloc((size_t)N * 4);
    int*   cnt     = (int*)  alloc((size_t)N * 4);
    int*   rowptr  = (int*)  alloc(((size_t)N + 1) * 4);
    int*   fill    = (int*)  alloc((size_t)N * 4);
    int*   partial = (int*)  alloc(1024 * 4);
    int*   csr_src = (int*)  alloc((size_t)E * 4);
    float* csr_w   = (float*)alloc((size_t)E * 4);
    float* lin     = (float*)alloc((size_t)N * HH * 4);
    float* hbuf    = (float*)alloc((size_t)N * HH * 4);

    const int B = 256;
    dim3 blk(B);
    int node_blocks = (N + 3) / 4;   // 4 waves/block, 1 node/wave
    int nB = (N + B - 1) / B;
    int eB = (E + B - 1) / B;
    int scanB = (N + SCAN_B - 1) / SCAN_B;   // 49 for N=50000

    // CSR build + normalization
    k_zero_int<<<nB, blk, 0, stream>>>(cnt, N);
    k_count<<<eB, blk, 0, stream>>>(col, E, cnt);
    k_scan_reduce<<<scanB, dim3(SCAN_B), 0, stream>>>(cnt, N, partial);
    k_scan_partials<<<1, dim3(1024), 0, stream>>>(partial, scanB, rowptr, N);
    k_scan_apply<<<scanB, dim3(SCAN_B), 0, stream>>>(cnt, partial, N, rowptr, fill, dinv);
    k_fill<<<eB, blk, 0, stream>>>(row, col, dinv, E, fill, csr_src, csr_w);

    // layer 1 (FIN=128)
    k_gemm<128><<<node_blocks, blk, 0, stream>>>(x, W1, lin, N);
    k_gather<<<node_blocks, blk, 0, stream>>>(lin, csr_src, csr_w, rowptr, dinv, b1, hbuf, N);
    // layer 2
    k_gemm<64><<<node_blocks, blk, 0, stream>>>(hbuf, W2, lin, N);
    k_gather<<<node_blocks, blk, 0, stream>>>(lin, csr_src, csr_w, rowptr, dinv, b2, hbuf, N);
    // layer 3 -> node_emb
    k_gemm<64><<<node_blocks, blk, 0, stream>>>(hbuf, W3, lin, N);
    k_gather<<<node_blocks, blk, 0, stream>>>(lin, csr_src, csr_w, rowptr, dinv, b3, node_emb, N);

    // pool + classifier
    k_final<<<G, dim3(64), 0, stream>>>(node_emb, batch, Wm, bm, logits, probs, graph_emb, N);
}